// Round 1
// baseline (527.157 us; speedup 1.0000x reference)
//
#include <hip/hip_runtime.h>
#include <hip/hip_bf16.h>

// StateDecoder: x[B=2048, C=2048] int32 bitmasks -> out[B, R=32, C] float32,
// out[b, i, c] = (x[b,c] >> i) & 1.
// Pure memory-bound broadcast: 16 MiB read, 512 MiB write.
//
// Layout strategy: thread t owns 4 consecutive c values of one row b.
//  - input:  one int4 load  (16 B/lane, coalesced -> global_load_dwordx4)
//  - output: 32 float4 stores, one per bit; across a wave the 64 lanes cover
//    256 consecutive c => each store is a fully coalesced 1 KiB transaction.

#define NUM_CANDIDATES 2048
#define NUM_REPLICAS   32
#define BATCH          2048

__global__ __launch_bounds__(256) void state_decoder_kernel(
    const int* __restrict__ x, float* __restrict__ out)
{
    constexpr int C = NUM_CANDIDATES;
    constexpr int R = NUM_REPLICAS;
    constexpr int CG = C / 4;               // groups of 4 c per row

    const unsigned tid = blockIdx.x * blockDim.x + threadIdx.x; // 0 .. B*C/4-1
    const unsigned b   = tid / CG;
    const unsigned cg  = tid - b * CG;      // group index within row
    // flat input offset of the 4 ints = b*C + cg*4 = tid*4  (since C % 4 == 0)
    const int4 xv = reinterpret_cast<const int4*>(x)[tid];

    float* outp = out + (size_t)b * (R * (size_t)C) + (size_t)cg * 4;

#pragma unroll
    for (int i = 0; i < R; ++i) {
        float4 v;
        v.x = (float)((xv.x >> i) & 1);
        v.y = (float)((xv.y >> i) & 1);
        v.z = (float)((xv.z >> i) & 1);
        v.w = (float)((xv.w >> i) & 1);
        *reinterpret_cast<float4*>(outp + (size_t)i * C) = v;
    }
}

extern "C" void kernel_launch(void* const* d_in, const int* in_sizes, int n_in,
                              void* d_out, int out_size, void* d_ws, size_t ws_size,
                              hipStream_t stream)
{
    const int* x = (const int*)d_in[0];
    float* out = (float*)d_out;

    const int total_threads = BATCH * NUM_CANDIDATES / 4;  // 1,048,576
    const int block = 256;
    const int grid = total_threads / block;                // 4096

    state_decoder_kernel<<<grid, block, 0, stream>>>(x, out);
}

// Round 2
// 524.724 us; speedup vs baseline: 1.0046x; 1.0046x over previous
//
#include <hip/hip_runtime.h>
#include <hip/hip_bf16.h>

// StateDecoder: x[B=2048, C=2048] int32 bitmasks -> out[B, R=32, C] float32,
// out[b, i, c] = (x[b,c] >> i) & 1.
//
// Round-2 structure: one block per row b.
//   1. Stage the row's 2048 ints (8 KiB) into LDS with coalesced int4 loads.
//   2. Sweep the row's output [32][2048] (256 KiB) in FLAT SEQUENTIAL order,
//      i-major: every block iteration stores 4 KiB contiguous, the block's
//      full output is one sequential 256 KiB stream (same pattern as the
//      6.1 TB/s fillBuffer). Round-1's 8 KiB-strided 32-stream-per-wave
//      writes ran at only ~3 TB/s.
// Bit index i is compile-time constant per unrolled iteration -> v_bfe const.

#define NUM_CANDIDATES 2048
#define NUM_REPLICAS   32
#define BATCH          2048

__global__ __launch_bounds__(256) void state_decoder_kernel(
    const int* __restrict__ x, float* __restrict__ out)
{
    constexpr int C = NUM_CANDIDATES;
    constexpr int R = NUM_REPLICAS;

    __shared__ int xs[C];  // 8 KiB

    const int b = blockIdx.x;
    const int t = threadIdx.x;  // 0..255

    // Cooperative row load: 2048 ints = 512 int4; 256 threads x 2 each.
    const int4* __restrict__ xrow = reinterpret_cast<const int4*>(x + (size_t)b * C);
    int4* xs4 = reinterpret_cast<int4*>(xs);
    xs4[t]       = xrow[t];
    xs4[t + 256] = xrow[t + 256];
    __syncthreads();

    float* __restrict__ orow = out + (size_t)b * (R * (size_t)C);

    // i-major sequential sweep: for each bit i, two half-row passes (h=0,1).
    // Store address = orow + i*2048 + h*1024 + t*4  -> block-wide 4 KiB
    // contiguous per (i,h); whole block output strictly sequential.
#pragma unroll
    for (int i = 0; i < R; ++i) {
#pragma unroll
        for (int h = 0; h < 2; ++h) {
            const int c = h * 1024 + t * 4;
            const int4 xv = *reinterpret_cast<const int4*>(&xs[c]);
            float4 v;
            v.x = (float)((xv.x >> i) & 1);
            v.y = (float)((xv.y >> i) & 1);
            v.z = (float)((xv.z >> i) & 1);
            v.w = (float)((xv.w >> i) & 1);
            *reinterpret_cast<float4*>(orow + i * C + c) = v;
        }
    }
}

extern "C" void kernel_launch(void* const* d_in, const int* in_sizes, int n_in,
                              void* d_out, int out_size, void* d_ws, size_t ws_size,
                              hipStream_t stream)
{
    const int* x = (const int*)d_in[0];
    float* out = (float*)d_out;

    state_decoder_kernel<<<BATCH, 256, 0, stream>>>(x, out);
}